// Round 2
// baseline (3557.994 us; speedup 1.0000x reference)
//
#include <hip/hip_runtime.h>
#include <hip/hip_bf16.h>

// Problem dims
#define S_LEN 128
#define M_B   256
#define E_DIM 1024
#define H_DIM 512
#define G4    2048          // 4*H
#define N_ROWS (S_LEN*M_B)  // 32768
#define KD    1024          // GEMM K for both layers (E = 2H = 1024)

typedef __bf16 bf16_t;
typedef __bf16 bf16x8 __attribute__((ext_vector_type(8)));
typedef float  f32x4  __attribute__((ext_vector_type(4)));

#define AS1(p) ((const __attribute__((address_space(1))) void*)(p))
#define AS3(p) ((__attribute__((address_space(3))) void*)(p))

__device__ __forceinline__ float sigm(float x)     { return 1.f / (1.f + __expf(-x)); }
__device__ __forceinline__ float tanhfast(float x) { return 2.f / (1.f + __expf(-2.f * x)) - 1.f; }

// ---------------------------------------------------------------------------
// Weight permutation + bf16 conversion.
// Gate permutation: j' = q*64 + gate*16 + u16  <->  j = gate*512 + (q*16+u16)
// so one 64-col group holds all 4 gates of 16 units; gate = n-frag index,
// unit = lane&15 (all 4 gates of a unit land in the same lane).
// ---------------------------------------------------------------------------
__global__ __launch_bounds__(256)
void permute_weights_kernel(const float* __restrict__ Wih, const float* __restrict__ Whh,
                            const float* __restrict__ b,
                            bf16_t* __restrict__ Wihp, bf16_t* __restrict__ Whhp,
                            float* __restrict__ bp)
{
    int bid = blockIdx.x;            // d*2048 + jp
    int d  = bid >> 11;
    int jp = bid & 2047;
    int q = jp >> 6, r = jp & 63;
    int gate = r >> 4, u16 = r & 15;
    int j = gate * H_DIM + q * 16 + u16;

    const float* s_ih = Wih + ((size_t)d * G4 + j) * E_DIM;
    bf16_t*      d_ih = Wihp + ((size_t)d * G4 + jp) * E_DIM;
    for (int e = threadIdx.x; e < E_DIM; e += 256) d_ih[e] = (bf16_t)s_ih[e];

    const float* s_hh = Whh + ((size_t)d * G4 + j) * H_DIM;
    bf16_t*      d_hh = Whhp + ((size_t)d * G4 + jp) * H_DIM;
    for (int k = threadIdx.x; k < H_DIM; k += 256) d_hh[k] = (bf16_t)s_hh[k];

    if (threadIdx.x == 0) bp[d * G4 + jp] = b[d * G4 + j];
}

// ---------------------------------------------------------------------------
// Embedding lookup -> bf16 X (32768 x 1024). emb[PAD_ID] is zero.
// ---------------------------------------------------------------------------
__global__ __launch_bounds__(256)
void embed_kernel(const int* __restrict__ F, const float* __restrict__ emb,
                  bf16_t* __restrict__ X)
{
    int n   = blockIdx.x;            // t*256 + m
    int tok = F[n];
    const float4* src = (const float4*)(emb + (size_t)tok * E_DIM);
    bf16_t*       dst = X + (size_t)n * E_DIM;
    for (int i = threadIdx.x; i < E_DIM / 4; i += 256) {
        float4 v = src[i];
        dst[i * 4 + 0] = (bf16_t)v.x;
        dst[i * 4 + 1] = (bf16_t)v.y;
        dst[i * 4 + 2] = (bf16_t)v.z;
        dst[i * 4 + 3] = (bf16_t)v.w;
    }
}

// ---------------------------------------------------------------------------
// srcrow[t*256+m] = ((t < L) ? L-1-t : t) * 256 + m   (self-inverse gather)
// ---------------------------------------------------------------------------
__global__ __launch_bounds__(256)
void rowmap_kernel(const int* __restrict__ F_lens, int* __restrict__ srcrow)
{
    int n = blockIdx.x * 256 + threadIdx.x;
    int t = n >> 8, m = n & 255;
    int L = F_lens[m];
    int st = (t < L) ? (L - 1 - t) : t;
    srcrow[n] = st * M_B + m;
}

// ---------------------------------------------------------------------------
// Chunked input-projection GEMM:
//   PREc[d][r][j'] = A[gather(rowbase+r)][:] . Wp[d][j'][:] + bp[d][j']
// d=0: natural rows; d=1: rows gathered via srcrow (pre-reversed input).
// 128x128 tile, BK=32, 4 waves 2x2, 16x16x32 bf16 MFMA, f32 out.
// ---------------------------------------------------------------------------
#define BM 128
#define BN 128
#define BK 32

__global__ __launch_bounds__(256)
void gemm_pre_kernel(const bf16_t* __restrict__ A,    // (32768, 1024) bf16
                     const bf16_t* __restrict__ Wp,   // (2, 2048, 1024) bf16
                     const float* __restrict__ bp,    // (2, 2048)
                     const int* __restrict__ srcrow,  // (32768)
                     float* __restrict__ PREc,        // (2, TCR, 2048)
                     int rowbase, int TCR)
{
    const int d    = blockIdx.z;
    const int n0   = blockIdx.x * BN;
    const int mloc = blockIdx.y * BM;
    const int tid  = threadIdx.x;
    const int lane = tid & 63, wave = tid >> 6;
    const int wm = wave >> 1, wn = wave & 1;
    const int fr = lane & 15, fq = lane >> 4;

    __shared__ __attribute__((aligned(16))) bf16_t At[BM * BK];
    __shared__ __attribute__((aligned(16))) bf16_t Bt[BN * BK];

    // Per-lane fixed staging rows (4 lanes per row, 16B chunks).
    const int r0 = tid >> 2;                 // 0..63
    const int k8 = (tid & 3) * 8;            // element offset of this 16B chunk
    const int n_0 = rowbase + mloc + r0;
    const int n_1 = n_0 + 64;
    const size_t srow0 = (d == 1) ? (size_t)srcrow[n_0] : (size_t)n_0;
    const size_t srow1 = (d == 1) ? (size_t)srcrow[n_1] : (size_t)n_1;
    const bf16_t* Ar0 = A + srow0 * KD + k8;
    const bf16_t* Ar1 = A + srow1 * KD + k8;
    const bf16_t* Br0 = Wp + ((size_t)d * G4 + n0 + r0) * KD + k8;
    const bf16_t* Br1 = Br0 + (size_t)64 * KD;

    f32x4 acc[4][4];
#pragma unroll
    for (int i = 0; i < 4; ++i)
#pragma unroll
        for (int j = 0; j < 4; ++j) { f32x4 z = {0.f, 0.f, 0.f, 0.f}; acc[i][j] = z; }

    for (int kt = 0; kt < KD; kt += BK) {
        __builtin_amdgcn_global_load_lds(AS1(Ar0 + kt), AS3(&At[(wave * 64) * 8]),       16, 0, 0);
        __builtin_amdgcn_global_load_lds(AS1(Ar1 + kt), AS3(&At[(256 + wave * 64) * 8]), 16, 0, 0);
        __builtin_amdgcn_global_load_lds(AS1(Br0 + kt), AS3(&Bt[(wave * 64) * 8]),       16, 0, 0);
        __builtin_amdgcn_global_load_lds(AS1(Br1 + kt), AS3(&Bt[(256 + wave * 64) * 8]), 16, 0, 0);
        __syncthreads();
        bf16x8 af[4], bff[4];
#pragma unroll
        for (int i = 0; i < 4; ++i) {
            af[i]  = *(const bf16x8*)&At[(wm * 64 + i * 16 + fr) * BK + fq * 8];
            bff[i] = *(const bf16x8*)&Bt[(wn * 64 + i * 16 + fr) * BK + fq * 8];
        }
#pragma unroll
        for (int i = 0; i < 4; ++i)
#pragma unroll
            for (int j = 0; j < 4; ++j)
                acc[i][j] = __builtin_amdgcn_mfma_f32_16x16x32_bf16(af[i], bff[j], acc[i][j], 0, 0, 0);
        __syncthreads();
    }

    const int cb = n0 + wn * 64 + fr;
#pragma unroll
    for (int mi = 0; mi < 4; ++mi) {
#pragma unroll
        for (int rr = 0; rr < 4; ++rr) {
            int r = mloc + wm * 64 + mi * 16 + fq * 4 + rr;
            float* prow = PREc + ((size_t)d * TCR + r) * G4;
#pragma unroll
            for (int ni = 0; ni < 4; ++ni) {
                int col = cb + ni * 16;
                prow[col] = acc[mi][ni][rr] + bp[d * G4 + col];
            }
        }
    }
}

// ---------------------------------------------------------------------------
// One recurrent step (both directions) fused with the LSTM cell.
// Grid (32 unit-groups, 4 m-tiles, 2 dirs) = 256 blocks, 256 threads.
// Per block: 64 m-rows x 64 gate-cols, full K=512 in one stage.
//  - Whh slice (64x512) -> LDS via global_load_lds, XOR-swizzled source +
//    matching swizzled ds_read (linear dest per rule 21).
//  - h rows -> VGPRs directly (af[16]).
// mode 0: h -> H1 (bf16). mode 1: h -> OUT (f32, masked).
// ---------------------------------------------------------------------------
__global__ __launch_bounds__(256)
void lstm_step_kernel(const bf16_t* __restrict__ hbin,  // (2,256,512) bf16
                      const bf16_t* __restrict__ Whhp,  // (2,2048,512) bf16
                      const float* __restrict__ PREc,   // (2,TCR,2048)
                      const int* __restrict__ F_lens,
                      float* __restrict__ cf,           // (2,256,512) f32 in-place
                      bf16_t* __restrict__ hbout,       // (2,256,512) bf16
                      bf16_t* __restrict__ H1,          // (32768,1024) bf16 (mode 0)
                      float* __restrict__ OUT,          // (32768,1024) f32 (mode 1)
                      int t, int tcoff, int TCR, int mode)
{
    const int d  = blockIdx.z;
    const int bx = blockIdx.x;          // unit group 0..31
    const int m0 = blockIdx.y * 64;
    const int tid = threadIdx.x;
    const int lane = tid & 63, wave = tid >> 6;
    const int fr = lane & 15, fq = lane >> 4;

    __shared__ __attribute__((aligned(16))) bf16_t Bt[64 * 512];   // 64 KiB

    // Stage B: 64 rows x 512 K = 4096 16B-chunks; 16 issues/thread.
    const bf16_t* Bg = Whhp + ((size_t)d * G4 + bx * 64) * H_DIM;
    {
        const int row = tid >> 6 | 0;  // recomputed per chunk below
    }
#pragma unroll
    for (int it = 0; it < 16; ++it) {
        int c   = it * 256 + tid;
        int row = c >> 6, ck = c & 63;
        int cks = ck ^ (row & 7);      // swizzle the SOURCE; dest stays linear
        __builtin_amdgcn_global_load_lds(AS1(Bg + (size_t)row * H_DIM + cks * 8),
                                         AS3(&Bt[(it * 256 + wave * 64) * 8]), 16, 0, 0);
    }

    // A rows direct to registers: lane covers row m0+wave*16+fr, k = ks*32+fq*8.
    const int mrow = m0 + wave * 16 + fr;
    const bf16_t* Arow = hbin + ((size_t)d * M_B + mrow) * H_DIM + fq * 8;
    bf16x8 af[16];
#pragma unroll
    for (int ks = 0; ks < 16; ++ks)
        af[ks] = *(const bf16x8*)(Arow + ks * 32);

    __syncthreads();   // waits vmcnt(0): LDS staging + af loads complete

    f32x4 acc[4];
#pragma unroll
    for (int j = 0; j < 4; ++j) { f32x4 z = {0.f, 0.f, 0.f, 0.f}; acc[j] = z; }

#pragma unroll
    for (int ks = 0; ks < 16; ++ks) {
#pragma unroll
        for (int j = 0; j < 4; ++j) {
            int rb = j * 16 + fr;
            int ck = (ks * 4 + fq) ^ (rb & 7);
            bf16x8 bf = *(const bf16x8*)&Bt[rb * 512 + ck * 8];
            acc[j] = __builtin_amdgcn_mfma_f32_16x16x32_bf16(af[ks], bf, acc[j], 0, 0, 0);
        }
    }

    // Fused LSTM cell epilogue. Each lane owns unit u for 4 m-rows.
    const int u     = bx * 16 + fr;
    const int cbcol = bx * 64 + fr;
#pragma unroll
    for (int rr = 0; rr < 4; ++rr) {
        int m = m0 + wave * 16 + fq * 4 + rr;
        int L = F_lens[m];
        bool mt = (t < L);
        int trow = (d == 0 || !mt) ? t : (L - 1 - t);
        const float* prow = PREc + ((size_t)d * TCR + (size_t)tcoff * M_B + m) * G4;
        float gi = acc[0][rr] + prow[cbcol];
        float gf = acc[1][rr] + prow[cbcol + 16];
        float gg = acc[2][rr] + prow[cbcol + 32];
        float go = acc[3][rr] + prow[cbcol + 48];
        int sidx = (d * M_B + m) * H_DIM + u;
        float cprev = cf[sidx];
        float c2 = sigm(gf) * cprev + sigm(gi) * tanhfast(gg);
        float h2 = sigm(go) * tanhfast(c2);
        if (!mt) { c2 = cprev; h2 = (float)hbin[sidx]; }
        cf[sidx]    = c2;
        hbout[sidx] = (bf16_t)h2;
        size_t orow = (size_t)trow * M_B + m;
        if (mode == 0) {
            H1[orow * 1024 + d * H_DIM + u] = (bf16_t)h2;
        } else {
            OUT[orow * 1024 + d * H_DIM + u] = mt ? h2 : 0.f;
        }
    }
}

// ---------------------------------------------------------------------------
extern "C" void kernel_launch(void* const* d_in, const int* in_sizes, int n_in,
                              void* d_out, int out_size, void* d_ws, size_t ws_size,
                              hipStream_t stream)
{
    const int*   F      = (const int*)d_in[0];
    const int*   F_lens = (const int*)d_in[1];
    const float* emb    = (const float*)d_in[2];
    const float* Wih0   = (const float*)d_in[3];
    const float* Whh0   = (const float*)d_in[4];
    const float* b0     = (const float*)d_in[5];
    const float* Wih1   = (const float*)d_in[6];
    const float* Whh1   = (const float*)d_in[7];
    const float* b1     = (const float*)d_in[8];
    float* OUT = (float*)d_out;

    // Base workspace (~155 MiB), 256B-aligned blocks.
    char* p = (char*)d_ws;
    auto alloc = [&](size_t bytes) { char* q = p; p += (bytes + 255) & ~(size_t)255; return (void*)q; };
    bf16_t* X0    = (bf16_t*)alloc((size_t)N_ROWS * E_DIM * 2);   // 64 MiB
    bf16_t* H1    = (bf16_t*)alloc((size_t)N_ROWS * 1024 * 2);    // 64 MiB
    bf16_t* Wih0p = (bf16_t*)alloc((size_t)2 * G4 * E_DIM * 2);   // 8 MiB
    bf16_t* Whh0p = (bf16_t*)alloc((size_t)2 * G4 * H_DIM * 2);   // 4 MiB
    bf16_t* Wih1p = (bf16_t*)alloc((size_t)2 * G4 * E_DIM * 2);   // 8 MiB
    bf16_t* Whh1p = (bf16_t*)alloc((size_t)2 * G4 * H_DIM * 2);   // 4 MiB
    float*  b0p   = (float*)alloc((size_t)2 * G4 * 4);
    float*  b1p   = (float*)alloc((size_t)2 * G4 * 4);
    int*    srcrow= (int*)alloc((size_t)N_ROWS * 4);              // 128 KiB
    bf16_t* hb0   = (bf16_t*)alloc((size_t)2 * M_B * H_DIM * 2);
    bf16_t* hb1   = (bf16_t*)alloc((size_t)2 * M_B * H_DIM * 2);
    float*  cfb   = (float*)alloc((size_t)2 * M_B * H_DIM * 4);
    size_t base_used = (size_t)(p - (char*)d_ws);

    // Largest time-chunk whose f32 PRE buffer fits the remaining workspace.
    int TC = 0;
    const int tcs[8] = {128, 64, 32, 16, 8, 4, 2, 1};
    for (int i = 0; i < 8; ++i) {
        size_t need = base_used + (size_t)2 * tcs[i] * M_B * G4 * 4;
        if (need <= ws_size) { TC = tcs[i]; break; }
    }
    if (TC == 0) return;  // cannot run at all
    float* PREc = (float*)p;
    const int TCR = TC * M_B;
    bf16_t* hb[2] = {hb0, hb1};

    permute_weights_kernel<<<dim3(2 * G4), 256, 0, stream>>>(Wih0, Whh0, b0, Wih0p, Whh0p, b0p);
    permute_weights_kernel<<<dim3(2 * G4), 256, 0, stream>>>(Wih1, Whh1, b1, Wih1p, Whh1p, b1p);
    embed_kernel<<<dim3(N_ROWS), 256, 0, stream>>>(F, emb, X0);
    rowmap_kernel<<<dim3(N_ROWS / 256), 256, 0, stream>>>(F_lens, srcrow);

    for (int layer = 0; layer < 2; ++layer) {
        const bf16_t* Xin  = layer ? H1 : X0;
        const bf16_t* Wihp = layer ? Wih1p : Wih0p;
        const bf16_t* Whhp = layer ? Whh1p : Whh0p;
        const float*  bp   = layer ? b1p : b0p;

        hipMemsetAsync(hb[0], 0, (size_t)2 * M_B * H_DIM * 2, stream);
        hipMemsetAsync(cfb,   0, (size_t)2 * M_B * H_DIM * 4, stream);

        for (int c = 0; c < S_LEN / TC; ++c) {
            gemm_pre_kernel<<<dim3(G4 / BN, TCR / BM, 2), 256, 0, stream>>>(
                Xin, Wihp, bp, srcrow, PREc, c * TCR, TCR);
            for (int tt = 0; tt < TC; ++tt) {
                int t = c * TC + tt;
                int pi = t & 1;
                lstm_step_kernel<<<dim3(32, 4, 2), 256, 0, stream>>>(
                    hb[pi], Whhp, PREc, F_lens, cfb, hb[pi ^ 1],
                    layer == 0 ? H1 : (bf16_t*)nullptr,
                    layer == 1 ? OUT : (float*)nullptr,
                    t, tt, TCR, layer);
            }
        }
    }
}